// Round 15
// baseline (214.521 us; speedup 1.0000x reference)
//
#include <hip/hip_runtime.h>
#include <hip/hip_bf16.h>
#include <math.h>

#define B_ 8
#define C_ 64
#define H_ 128
#define W_ 128
#define HW_ (H_*W_)
#define HP_ 130
#define WP_ 130
#define XPLANE_ (HP_*WP_*64)     // padded NHWC plane per batch (halfwords)

typedef __attribute__((ext_vector_type(8))) short bf16x8;
typedef __attribute__((ext_vector_type(4))) float f32x4;
typedef __attribute__((ext_vector_type(4))) unsigned int u32x4;

// ---------------------------------------------------------------------------
// Weight transpose+cast helper: w fp32 [O][64][9] -> wT bf16 [9][OPAD][64]
// ---------------------------------------------------------------------------
__device__ __forceinline__ void cast_one(const float* __restrict__ w,
                                         __hip_bfloat16* __restrict__ wT,
                                         int O, int OPAD, int idx)
{
    if (idx >= 9*O*64) return;
    const int k = idx / (O*64);
    const int rem = idx - k*O*64;
    const int o = rem >> 6, c = rem & 63;
    wT[((size_t)k*OPAD + o)*64 + c] = __float2bfloat16(w[((size_t)o*64 + c)*9 + k]);
}

// ---------------------------------------------------------------------------
// PREP (one launch): halo zeroing (blocks 0..23), wT3 pad-row zeroing (24),
// all weight casts (25..969), x NCHW fp32 -> padded NHWC bf16 (970..3017).
// ---------------------------------------------------------------------------
__global__ __launch_bounds__(256)
void prep_k(const float* __restrict__ x,
            const float* __restrict__ w1, const float* __restrict__ w2,
            const float* __restrict__ w3, const float* __restrict__ wa,
            const float* __restrict__ wd,
            __hip_bfloat16* __restrict__ xTp, __hip_bfloat16* __restrict__ m1Tp,
            __hip_bfloat16* __restrict__ m2Tp,
            __hip_bfloat16* __restrict__ wT1, __hip_bfloat16* __restrict__ wT2,
            __hip_bfloat16* __restrict__ wT3, __hip_bfloat16* __restrict__ wTa,
            __hip_bfloat16* __restrict__ wTd)
{
    __shared__ float tile[64][65];
    const int bx = blockIdx.x, tid = threadIdx.x;
    if (bx < 24){
        const int plane = bx >> 3, batch = bx & 7;
        __hip_bfloat16* pl = (plane==0) ? xTp : ((plane==1) ? m1Tp : m2Tp);
        unsigned int* base = (unsigned int*)pl + (size_t)batch*(XPLANE_/2);
        for (int i = tid; i < 516*32; i += 256){
            const int u = i & 31, p = i >> 5;
            int h, w;
            if (p < 130)      { h = 0;        w = p;       }
            else if (p < 260) { h = 129;      w = p - 130; }
            else if (p < 388) { h = p - 259;  w = 0;       }
            else              { h = p - 387;  w = 129;     }
            base[(size_t)(h*130 + w)*32 + u] = 0u;
        }
    } else if (bx == 24){
        unsigned int* w3u = (unsigned int*)wT3;
        for (int i = tid; i < 3456; i += 256){
            const int k = i / 384, rem = i - k*384;
            w3u[k*1536 + 1152 + rem] = 0u;
        }
    } else if (bx < 970){
        const int cbx = bx - 25;
        if      (cbx < 144) cast_one(w1, wT1,  64,  64, cbx*256 + tid);
        else if (cbx < 288) cast_one(w2, wT2,  64,  64, (cbx-144)*256 + tid);
        else if (cbx < 369) cast_one(w3, wT3,  36,  48, (cbx-288)*256 + tid);
        else if (cbx < 657) cast_one(wa, wTa, 128, 128, (cbx-369)*256 + tid);
        else                cast_one(wd, wTd, 128, 128, (cbx-657)*256 + tid);
    } else {
        const int i = bx - 970;
        const int w0 = (i & 1)*64, h = (i >> 1) & 127, b = i >> 8;
        const float* xb = x + (size_t)b*64*HW_;
        for (int j = tid; j < 4096; j += 256){
            const int c = j >> 6, px = j & 63;
            tile[c][px] = xb[(size_t)c*HW_ + h*W_ + w0 + px];
        }
        __syncthreads();
        __hip_bfloat16* ob = xTp + (size_t)b*XPLANE_;
        for (int j = tid; j < 512; j += 256){
            const int px = j >> 3, cs = j & 7;
            union { bf16x8 v; __hip_bfloat16 h8[8]; } R;
#pragma unroll
            for (int q=0;q<8;q++) R.h8[q] = __float2bfloat16(tile[cs*8+q][px]);
            *(bf16x8*)&ob[((size_t)(h+1)*WP_ + (w0+px+1))*64 + cs*8] = R.v;
        }
    }
}

// ---------------------------------------------------------------------------
// Implicit-GEMM 3x3 conv via MFMA, wide: 512 threads, 128-px full row/block.
// NHWC padded + ReLU output. (conv1, conv2.)
// ---------------------------------------------------------------------------
template<int G>
__global__ __launch_bounds__(512)
void conv_mfma_k(const __hip_bfloat16* __restrict__ xT,
                 const __hip_bfloat16* __restrict__ wT, int o_total,
                 __hip_bfloat16* __restrict__ outp)
{
    __shared__ __hip_bfloat16 wA[G*16][64];
    const int tid = threadIdx.x, lane = tid & 63, wid = tid >> 6;
    const int l15 = lane & 15, khi = lane >> 4;
    const int oh = blockIdx.x;
    const int b = blockIdx.z;
    const int px = wid*16 + l15;
    const __hip_bfloat16* xb = xT + (size_t)b*XPLANE_;

    f32x4 acc[G];
    const f32x4 vz = {0.f,0.f,0.f,0.f};
#pragma unroll
    for (int g=0; g<G; ++g) acc[g] = vz;

    for (int k=0; k<9; ++k){
        const int dy = k/3 - 1, dxk = k%3 - 1;
        __syncthreads();
        if (tid < G*16*8){
            const int o = tid >> 3, cs = tid & 7;
            *(bf16x8*)&wA[o][((cs ^ (o&7))*8)] =
                *(const bf16x8*)&wT[((size_t)k*o_total + o)*64 + cs*8];
        }
        __syncthreads();
        const int base = (((oh+1+dy)*WP_) + (px+1+dxk))*64;
#pragma unroll
        for (int s=0; s<2; ++s){
            const bf16x8 bfr = *(const bf16x8*)&xb[base + s*32 + khi*8];
            const int c8 = ((s*4 + khi) ^ (l15 & 7))*8;
#pragma unroll
            for (int g=0; g<G; ++g){
                const bf16x8 afr = *(const bf16x8*)&wA[g*16 + l15][c8];
                acc[g] = __builtin_amdgcn_mfma_f32_16x16x32_bf16(afr, bfr, acc[g], 0,0,0);
            }
        }
    }
    __hip_bfloat16* ob = outp + (size_t)b*XPLANE_;
    const size_t orow = ((size_t)(oh+1)*WP_ + (px+1))*64;
#pragma unroll
    for (int g=0; g<G; ++g){
        union { short4 s4; __hip_bfloat16 h[4]; } o4;
#pragma unroll
        for (int r=0;r<4;r++) o4.h[r] = __float2bfloat16(fmaxf(acc[g][r], 0.f));
        *(short4*)&ob[orow + g*16 + khi*4] = o4.s4;
    }
}

// ---------------------------------------------------------------------------
// MERGED K3 (R13-proven): z<8 -> offs conv (m2 -> offsb bf16 NCHW, 36 ch);
//                         z>=8 -> att conv (x -> attn bf16 NHWC-128).
// Runs AFTER conv2, so m1 is dead and attn may alias the m1 region.
// ---------------------------------------------------------------------------
__global__ __launch_bounds__(512)
void conv3_att_k(const __hip_bfloat16* __restrict__ m2T,
                 const __hip_bfloat16* __restrict__ xT,
                 const __hip_bfloat16* __restrict__ wT3,   // [9][48][64]
                 const __hip_bfloat16* __restrict__ wTa,   // [9][128][64]
                 __hip_bfloat16* __restrict__ offsb,       // [b][36][128][128]
                 __hip_bfloat16* __restrict__ attn)        // [b][h][w][128]
{
    __shared__ __hip_bfloat16 wA[64][64];
    const int tid = threadIdx.x, lane = tid & 63, wid = tid >> 6;
    const int l15 = lane & 15, khi = lane >> 4;
    const int oh = blockIdx.x;
    const int px = wid*16 + l15;
    const f32x4 vz = {0.f,0.f,0.f,0.f};

    if (blockIdx.z < 8){
        const int b = blockIdx.z;
        const __hip_bfloat16* xb = m2T + (size_t)b*XPLANE_;
        f32x4 acc[3];
#pragma unroll
        for (int g=0; g<3; ++g) acc[g] = vz;
        for (int k=0; k<9; ++k){
            const int dy = k/3 - 1, dxk = k%3 - 1;
            __syncthreads();
            if (tid < 384){
                const int o = tid >> 3, cs = tid & 7;
                *(bf16x8*)&wA[o][((cs ^ (o&7))*8)] =
                    *(const bf16x8*)&wT3[((size_t)k*48 + o)*64 + cs*8];
            }
            __syncthreads();
            const int base = (((oh+1+dy)*WP_) + (px+1+dxk))*64;
#pragma unroll
            for (int s=0; s<2; ++s){
                const bf16x8 bfr = *(const bf16x8*)&xb[base + s*32 + khi*8];
                const int c8 = ((s*4 + khi) ^ (l15 & 7))*8;
#pragma unroll
                for (int g=0; g<3; ++g){
                    const bf16x8 afr = *(const bf16x8*)&wA[g*16 + l15][c8];
                    acc[g] = __builtin_amdgcn_mfma_f32_16x16x32_bf16(afr, bfr, acc[g], 0,0,0);
                }
            }
        }
#pragma unroll
        for (int g=0; g<3; ++g)
#pragma unroll
            for (int r=0;r<4;r++){
                const int co = g*16 + khi*4 + r;
                if (co < 36)
                    offsb[(((size_t)b*36 + co)*H_ + oh)*W_ + px] =
                        __float2bfloat16(acc[g][r]);
            }
    } else {
        const int zz = blockIdx.z - 8, b = zz & 7, dkb = zz >> 3;
        const __hip_bfloat16* xb = xT + (size_t)b*XPLANE_;
        f32x4 acc[4];
#pragma unroll
        for (int g=0; g<4; ++g) acc[g] = vz;
        for (int k=0; k<9; ++k){
            const int dy = k/3 - 1, dxk = k%3 - 1;
            __syncthreads();
            {
                const int o = tid >> 3, cs = tid & 7;
                *(bf16x8*)&wA[o][((cs ^ (o&7))*8)] =
                    *(const bf16x8*)&wTa[((size_t)k*128 + dkb*64 + o)*64 + cs*8];
            }
            __syncthreads();
            const int base = (((oh+1+dy)*WP_) + (px+1+dxk))*64;
#pragma unroll
            for (int s=0; s<2; ++s){
                const bf16x8 bfr = *(const bf16x8*)&xb[base + s*32 + khi*8];
                const int c8 = ((s*4 + khi) ^ (l15 & 7))*8;
#pragma unroll
                for (int g=0; g<4; ++g){
                    const bf16x8 afr = *(const bf16x8*)&wA[g*16 + l15][c8];
                    acc[g] = __builtin_amdgcn_mfma_f32_16x16x32_bf16(afr, bfr, acc[g], 0,0,0);
                }
            }
        }
        __hip_bfloat16* ab = attn + ((size_t)b*HW_ + (size_t)oh*W_ + px)*128 + dkb*64;
#pragma unroll
        for (int g=0; g<4; ++g){
            union { short4 s4; __hip_bfloat16 h[4]; } o4;
#pragma unroll
            for (int r=0;r<4;r++) o4.h[r] = __float2bfloat16(acc[g][r]);
            *(short4*)&ab[g*16 + khi*4] = o4.s4;
        }
    }
}

// ---------------------------------------------------------------------------
// 4-corner bilinear blend of 8 consecutive channels (NHWC bf16) -> bf16x8.
// ---------------------------------------------------------------------------
__device__ __forceinline__ bf16x8 blend4(const __hip_bfloat16* __restrict__ xb,
                                         int a00, int dxo, int dro, float4 w)
{
    const u32x4 q00 = *(const u32x4*)(xb + a00);
    const u32x4 q01 = *(const u32x4*)(xb + a00 + dxo);
    const u32x4 q10 = *(const u32x4*)(xb + a00 + dro);
    const u32x4 q11 = *(const u32x4*)(xb + a00 + dro + dxo);
    union { bf16x8 v; __hip_bfloat16 h[8]; } R;
#pragma unroll
    for (int p=0;p<4;++p){
        const float l00 = __uint_as_float(q00[p]<<16), h00 = __uint_as_float(q00[p]&0xFFFF0000u);
        const float l01 = __uint_as_float(q01[p]<<16), h01 = __uint_as_float(q01[p]&0xFFFF0000u);
        const float l10 = __uint_as_float(q10[p]<<16), h10 = __uint_as_float(q10[p]&0xFFFF0000u);
        const float l11 = __uint_as_float(q11[p]<<16), h11 = __uint_as_float(q11[p]&0xFFFF0000u);
        R.h[2*p  ] = __float2bfloat16(w.x*l00 + w.y*l01 + w.z*l10 + w.w*l11);
        R.h[2*p+1] = __float2bfloat16(w.x*h00 + w.y*h01 + w.z*h10 + w.w*h11);
    }
    return R.v;
}

// ---------------------------------------------------------------------------
// Fused deformable conv (MFMA) + softmax attention, v9:
// R13 octet-gather structure + meta-LDS trim (int4 -> int + packed dxo|dro):
// LDS 43008 -> 38400 B => 4 blocks/CU (was 3).
// ---------------------------------------------------------------------------
__global__ __launch_bounds__(256)
void deform_att_k(const __hip_bfloat16* __restrict__ xT,
                  const __hip_bfloat16* __restrict__ offsb,
                  const __hip_bfloat16* __restrict__ attn,
                  const __hip_bfloat16* __restrict__ wTd,   // [9][128][64]
                  float* __restrict__ out)
{
    __shared__ __hip_bfloat16 wA[2][64][64];        // 16 KB  [buf][co][c] swz
    __shared__ int    mA [9][64];                   // 2.25 KB  a00
    __shared__ int    mDD[9][64];                   // 2.25 KB  (dro<<16)|dxo
    __shared__ float4 mW [9][64];                   // 9 KB     (w00,w01,w10,w11)
    __shared__ __hip_bfloat16 samp[4][16][64];      // 8 KB  [wave][px16][ch] swz
    const int tid = threadIdx.x, lane = tid & 63, wid = tid >> 6;
    const int l15 = lane & 15, khi = lane >> 4;
    const int lp  = lane >> 3, lc = lane & 7;       // octet px / ch-chunk
    const int ow0 = blockIdx.x*64, oh = blockIdx.y, b = blockIdx.z;
    const int px = wid*16 + l15;
    const __hip_bfloat16* xb = xT + (size_t)b*XPLANE_;
    const int srow = tid >> 3, scs = tid & 7;
    const int swz = (scs ^ (srow & 7)) * 8;

    f32x4 acc[2][4];
    const f32x4 vz = {0.f,0.f,0.f,0.f};
#pragma unroll
    for (int d=0; d<2; ++d)
#pragma unroll
        for (int g=0; g<4; ++g) acc[d][g] = vz;

    // ---- prologue: stage tap (dk0,k0) weights into wA[0] ----
    {
        const __hip_bfloat16* ws0 = &wTd[(size_t)srow*64 + scs*8];
        *(bf16x8*)&wA[0][srow   ][swz] = *(const bf16x8*)ws0;
        *(bf16x8*)&wA[0][srow+32][swz] = *(const bf16x8*)(ws0 + 32*64);
    }

#pragma unroll
    for (int dk=0; dk<2; ++dk){
        // ---- stage bilinear meta for this dk (9 taps x 64 px) ----
        for (int e=tid; e<576; e+=256){
            const int k = e >> 6, p = e & 63;
            const float oy = __bfloat162float(
                offsb[(((size_t)b*36 + dk*18 + 2*k  )*H_ + oh)*W_ + ow0 + p]);
            const float ox = __bfloat162float(
                offsb[(((size_t)b*36 + dk*18 + 2*k+1)*H_ + oh)*W_ + ow0 + p]);
            const float py  = (float)(oh  - 1 + (k/3))      + oy;
            const float pxx = (float)(ow0 + p - 1 + (k%3))  + ox;
            const float y0f = floorf(py), x0f = floorf(pxx);
            const float ay = py - y0f, ax = pxx - x0f;
            const int y0 = (int)y0f, x0 = (int)x0f;
            const int y1 = y0 + 1,   x1 = x0 + 1;
            const float my0 = (y0 >= 0 && y0 < H_) ? 1.f : 0.f;
            const float my1 = (y1 >= 0 && y1 < H_) ? 1.f : 0.f;
            const float mx0 = (x0 >= 0 && x0 < W_) ? 1.f : 0.f;
            const float mx1 = (x1 >= 0 && x1 < W_) ? 1.f : 0.f;
            const int y0c = min(max(y0,0),H_-1), y1c = min(max(y1,0),H_-1);
            const int x0c = min(max(x0,0),W_-1), x1c = min(max(x1,0),W_-1);
            const float wy0 = my0*(1.f-ay), wy1 = my1*ay;
            const float wx0 = mx0*(1.f-ax), wx1 = mx1*ax;
            mA [k][p] = ((y0c+1)*WP_ + (x0c+1))*64;
            mDD[k][p] = (((y1c-y0c)*WP_*64) << 16) | ((x1c-x0c)*64);
            mW [k][p] = make_float4(wy0*wx0, wy0*wx1, wy1*wx0, wy1*wx1);
        }
        __syncthreads();   // meta visible; prologue/prefetched wA visible

        for (int k=0; k<9; ++k){
            const int t = dk*9 + k;
            // ---- prefetch next tap's weights into registers ----
            bf16x8 nw0 = {}, nw1 = {};
            const bool hn = (t < 17);
            const int ndk = (k==8) ? dk+1 : dk;
            const int nk  = (k==8) ? 0 : k+1;
            if (hn){
                const __hip_bfloat16* ws0 =
                    &wTd[((size_t)nk*128 + ndk*64 + srow)*64 + scs*8];
                nw0 = *(const bf16x8*)ws0;
                nw1 = *(const bf16x8*)(ws0 + 32*64);
            }
            // ---- octet gathers: 2 octets x 4 corners, 8 px x 128B each ----
#pragma unroll
            for (int oct=0; oct<2; ++oct){
                const int pxo = wid*16 + oct*8 + lp;
                const int a00 = mA[k][pxo];      // broadcast among 8 lanes
                const int dd  = mDD[k][pxo];
                const float4 mw = mW[k][pxo];
                const bf16x8 v = blend4(xb, a00 + lc*8, dd & 0xFFFF, dd >> 16, mw);
                const int row = oct*8 + lp;
                *(bf16x8*)&samp[wid][row][((lc ^ (row & 7))*8)] = v;
            }
            // ---- fragment reads (wave-private, no barrier) + MFMA ----
            const __hip_bfloat16 (*wr)[64] = (const __hip_bfloat16 (*)[64])wA[t & 1];
#pragma unroll
            for (int s=0; s<2; ++s){
                const int c8 = ((s*4 + khi) ^ (l15 & 7))*8;
                const bf16x8 bfr = *(const bf16x8*)&samp[wid][l15][c8];
#pragma unroll
                for (int g=0; g<4; ++g){
                    const bf16x8 afr = *(const bf16x8*)&wr[g*16 + l15][c8];
                    acc[dk][g] = __builtin_amdgcn_mfma_f32_16x16x32_bf16(afr, bfr, acc[dk][g], 0,0,0);
                }
            }
            // ---- late ds_write of prefetched weights ----
            if (hn){
                *(bf16x8*)&wA[(t+1)&1][srow   ][swz] = nw0;
                *(bf16x8*)&wA[(t+1)&1][srow+32][swz] = nw1;
            }
            __syncthreads();   // wA[t&1] reads done; wA[(t+1)&1] visible
        }
    }
    // ---- epilogue: NHWC-128 att reads + softmax + write ----
    const __hip_bfloat16* ab = attn + ((size_t)b*HW_ + (size_t)oh*W_ + ow0 + px)*128;
#pragma unroll
    for (int g=0; g<4; ++g){
        union { short4 s4; __hip_bfloat16 h[4]; } a0v, a1v;
        a0v.s4 = *(const short4*)&ab[     g*16 + khi*4];
        a1v.s4 = *(const short4*)&ab[64 + g*16 + khi*4];
#pragma unroll
        for (int r=0; r<4; ++r){
            const int co = g*16 + khi*4 + r;
            const float a0 = __bfloat162float(a0v.h[r]);
            const float a1 = __bfloat162float(a1v.h[r]);
            const float f0 = 1.f / (1.f + __expf(a1 - a0));
            out[(((size_t)b*64 + co)*H_ + oh)*W_ + ow0 + px] =
                acc[0][g][r]*f0 + acc[1][g][r]*(1.f - f0);
        }
    }
}

// ---------------------------------------------------------------------------
extern "C" void kernel_launch(void* const* d_in, const int* in_sizes, int n_in,
                              void* d_out, int out_size, void* d_ws, size_t ws_size,
                              hipStream_t stream)
{
    const float* x  = (const float*)d_in[0];
    const float* w1 = (const float*)d_in[1];
    const float* w2 = (const float*)d_in[2];
    const float* w3 = (const float*)d_in[3];
    const float* wa = (const float*)d_in[4];
    const float* wd = (const float*)d_in[5];
    float* out = (float*)d_out;

    // ---- workspace layout (halfword units), total ~78.1 MB ----
    __hip_bfloat16* xTp   = (__hip_bfloat16*)d_ws;       // 8,652,800
    __hip_bfloat16* m2Tp  = xTp   + (size_t)8652800;     // 8,652,800
    __hip_bfloat16* wT1   = m2Tp  + (size_t)8652800;     // 36864
    __hip_bfloat16* wT2   = wT1   + 36864;               // 36864
    __hip_bfloat16* wT3   = wT2   + 36864;               // 27648
    __hip_bfloat16* wTa   = wT3   + 27648;               // 73728
    __hip_bfloat16* wTd   = wTa   + 73728;               // 73728
    __hip_bfloat16* offsb = wTd   + 73728;               // 4,718,592 (bf16 NCHW)
    __hip_bfloat16* m1Tp  = offsb + (size_t)4718592;     // 8,652,800
    __hip_bfloat16* attn  = m1Tp;   // aliases m1 region (m1 dead after conv2)

    const dim3 blk(256), blkw(512);
    prep_k<<<dim3(3018), blk, 0, stream>>>(x, w1,w2,w3,wa,wd,
                                           xTp, m1Tp, m2Tp,
                                           wT1, wT2, wT3, wTa, wTd);
    conv_mfma_k<4><<<dim3(128,1,8), blkw, 0, stream>>>(xTp,  wT1, 64, m1Tp);
    conv_mfma_k<4><<<dim3(128,1,8), blkw, 0, stream>>>(m1Tp, wT2, 64, m2Tp);
    // merged: offs conv (z<8) + att conv (z>=8); m1 dead -> attn alias valid
    conv3_att_k<<<dim3(128,1,24), blkw, 0, stream>>>(m2Tp, xTp, wT3, wTa,
                                                     offsb, attn);
    // fused deformable conv + attention (v9: octet gathers + 4 blocks/CU)
    deform_att_k<<<dim3(2,128,8), blk, 0, stream>>>(xTp, offsb, attn, wTd, out);
}